// Round 11
// baseline (119.071 us; speedup 1.0000x reference)
//
#include <hip/hip_runtime.h>

#define KCODES 16384
#define CDIM   32
#define NROWS  8192
#define KSPLIT 8                  // chunks (blockIdx.y)
#define CHUNK  (KCODES/KSPLIT)    // 2048
#define WCODES (CHUNK/4)          // 512 codes per wave
#define NT     (WCODES/16)        // 32 MFMA code-tiles per wave
#define RPB    32                 // rows per block (v11: back to 32 -> 50 live
                                  // VGPRs -> lb(256,8) = 8 waves/SIMD)
#define MARGIN 4.0f               // >>(f16 mfma err ~0.8 + tag noise ~0.2) in l-units

typedef _Float16 half8 __attribute__((ext_vector_type(8)));
typedef float    floatx4 __attribute__((ext_vector_type(4)));

// workspace layout (float indices)
#define WS_MSE   0
#define WS_PLP   1
#define WS_AVGP  16                      // [16384]
#define WS_ENORM (16 + KCODES)           // [16384] fp32, exact
#define WS_ZNORM (16 + 2*KCODES)         // [8192]  fp32
#define WS_PART  (16 + 2*KCODES + NROWS) // float4[KSPLIT][NROWS]
#define WS_E16   (WS_PART + 4*KSPLIT*NROWS)      // f16[16384][32]
#define WS_Z16   (WS_E16 + KCODES*16)            // f16[8192][32]
#define WS_ENH   (WS_Z16 + NROWS*16)     // [16384] fp32 = -0.5*enorm

// output layout (floats): z_q [0, N*C), loss [N*C], idx [N*C+1, ...)
#define OUT_LOSS (NROWS*CDIM)
#define OUT_IDX  (NROWS*CDIM + 1)

// ---------------------------------------------------------------------------
// prep: blocks [0,64): e-rows (enorm + ENH + f16 + zero avg_probs);
// blocks [64,96): z-rows (znorm + f16); block 64 zeroes scalars.
// ---------------------------------------------------------------------------
__global__ __launch_bounds__(256) void prep_kernel(const float* __restrict__ z,
                                                   const float* __restrict__ emb,
                                                   float* __restrict__ ws) {
  const int tid = threadIdx.x;
  if (blockIdx.x < 64) {
    int k = blockIdx.x * 256 + tid;
    const float4* p = (const float4*)(emb + (size_t)k * CDIM);
    _Float16* e16 = (_Float16*)(ws + WS_E16);
    float s = 0.f;
    half8 h[4];
#pragma unroll
    for (int i = 0; i < 8; ++i) {
      float4 v = p[i];
      s += v.x*v.x + v.y*v.y + v.z*v.z + v.w*v.w;
      h[i>>1][(i&1)*4+0] = (_Float16)v.x;
      h[i>>1][(i&1)*4+1] = (_Float16)v.y;
      h[i>>1][(i&1)*4+2] = (_Float16)v.z;
      h[i>>1][(i&1)*4+3] = (_Float16)v.w;
    }
    ws[WS_ENORM + k] = s;
    ws[WS_ENH + k]   = -0.5f * s;       // exact: sign+exponent ops only
    ws[WS_AVGP + k]  = 0.f;
    half8* dst = (half8*)(e16 + (size_t)k*32);
#pragma unroll
    for (int i = 0; i < 4; ++i) dst[i] = h[i];
  } else {
    int b = blockIdx.x - 64;
    int n = b*256 + tid;
    if (b == 0 && tid < 16) ws[tid] = 0.f;
    _Float16* z16 = (_Float16*)(ws + WS_Z16);
    float s = 0.f;
    half8 h[4];
#pragma unroll
    for (int c = 0; c < CDIM; ++c) {
      float v = z[(size_t)b*8192 + c*256 + tid];
      s = fmaf(v, v, s);
      h[c>>3][c&7] = (_Float16)v;
    }
    ws[WS_ZNORM + n] = s;
    half8* dst = (half8*)(z16 + (size_t)n*32);
#pragma unroll
    for (int i = 0; i < 4; ++i) dst[i] = h[i];
  }
}

// ---------------------------------------------------------------------------
// gemm_pass v11: lean screen + MAX TLP. Evidence chain:
//   R8: Occupancy 27% (never explained); b-stream is streaming (L2-resident,
//   never L1-hot, ~200+cyc/load); prefetch slack ~1.5 phases only covers it
//   at >=6-8 waves/SIMD. R5 tested 8 waves with the FAT screen (issue-bound
//   -> TLP irrelevant). R10 built the lean 3-op screen at RPB=64 (98 live
//   regs -> 8 waves impossible) -> got half the predicted gain = latency
//   became co-limiter. v11 combines them: RPB=32 => live ~50 VGPRs
//   (zb 8, t 4, bc/bn 8, e4 8, d 8, addr 12) => lb(256,8), grid 2048 blocks
//   = 8 blocks/CU x 4 waves = full 32-slot residency.
// part[] bit-identical (same per-(row,chunk) stream, tags, merge values).
// PRE-COMMIT: total >= 112us => ROOFLINE next round (fills = 80us @ 83%
// HBM peak dominate; gemm has resisted 7 mechanisms).
// ---------------------------------------------------------------------------
__global__ __launch_bounds__(256, 8) void gemm_pass(const float* __restrict__ ws_ro,
                                                    float* __restrict__ ws) {
  __shared__ float2 wdump[4][RPB];      // [wave][row] top-2 tagged floats

  const int tid  = threadIdx.x;
  const int wv   = tid >> 6;
  const int lane = tid & 63;
  const int nn   = lane & 15;
  const int quad = lane >> 4;
  const int n0   = blockIdx.x * RPB;
  const int kb   = blockIdx.y * CHUNK + wv * WCODES;

  const half8* z16v = (const half8*)(ws_ro + WS_Z16);
  const half8* e16v = (const half8*)(ws_ro + WS_E16);
  const float* enh   = ws_ro + WS_ENH;
  const float* znorm = ws_ro + WS_ZNORM;
  float4* part = (float4*)(ws + WS_PART);

  // z-row B-fragments (lane nn <-> z-row of each 16-row group)
  half8 zb0 = z16v[(size_t)(n0 + nn)*4 + quad];
  half8 zb1 = z16v[(size_t)(n0 + 16 + nn)*4 + quad];

  // per-lane top-2 state: 2 row-groups, row (g*16+nn), codes {quad*4+j}
  float t1[2], t2[2];
#pragma unroll
  for (int g = 0; g < 2; ++g) { t1[g] = -3.0e38f; t2[g] = -3.0e38f; }

  // tag bases: code = wv*512 | 16t | quad*4+j  (disjoint bit fields)
  const int tgq = wv*WCODES + quad*4;
  const int tgq0 = tgq, tgq1 = tgq|1, tgq2 = tgq|2, tgq3 = tgq|3;
  const unsigned maskhi = 0xFFFFF000u;  // hoisted to SGPR by "s" constraint

  // code A-fragment pointer (lane nn <-> code row of tile): 64 half8/tile
  const half8* pb = e16v + ((size_t)(kb + nn)*4 + quad);
  // ENH per-lane float4 (pre-negated-halved enorm): 4 float4/tile
  const float4* pq = (const float4*)(enh + kb) + quad;

#define SCREEN1(dv, vt, g)                                                  \
  { float _tmp;                                                             \
    asm("v_and_or_b32 %2, %3, %4, %5\n\t"                                   \
        "v_med3_f32 %1, %2, %0, %1\n\t"                                     \
        "v_max_f32 %0, %2, %0"                                              \
        : "+v"(t1[g]), "+v"(t2[g]), "=&v"(_tmp)                             \
        : "v"(dv), "s"(maskhi), "v"(vt)); }

  half8 bc = pb[0];  float4 e4c = pq[0];   // tile t
  half8 bn;          float4 e4n;           // tile t+1

  for (int t = 0; t < NT; t += 2) {
    // ---- phase A: prefetch t+1, compute tile t ----
    bn = pb[64];  e4n = pq[4];
    {
      floatx4 cb = {e4c.x, e4c.y, e4c.z, e4c.w};   // bias pre-negated in prep
      floatx4 d0 = __builtin_amdgcn_mfma_f32_16x16x32_f16(bc, zb0, cb, 0, 0, 0);
      floatx4 d1 = __builtin_amdgcn_mfma_f32_16x16x32_f16(bc, zb1, cb, 0, 0, 0);
      asm("" : "+v"(d0), "+v"(d1));                // arch-VGPR pin
      const int s16t = 16*t;
      const int vt0 = tgq0 | s16t, vt1 = tgq1 | s16t,
                vt2 = tgq2 | s16t, vt3 = tgq3 | s16t;
      SCREEN1(d0[0], vt0, 0) SCREEN1(d0[1], vt1, 0)
      SCREEN1(d0[2], vt2, 0) SCREEN1(d0[3], vt3, 0)
      SCREEN1(d1[0], vt0, 1) SCREEN1(d1[1], vt1, 1)
      SCREEN1(d1[2], vt2, 1) SCREEN1(d1[3], vt3, 1)
    }
    // ---- phase B: prefetch t+2 (overwrites consumed bc), compute t+1 ----
    bc = pb[128];  e4c = pq[8];               // last iter: mapped overread, unused
    {
      floatx4 cb = {e4n.x, e4n.y, e4n.z, e4n.w};
      floatx4 d0 = __builtin_amdgcn_mfma_f32_16x16x32_f16(bn, zb0, cb, 0, 0, 0);
      floatx4 d1 = __builtin_amdgcn_mfma_f32_16x16x32_f16(bn, zb1, cb, 0, 0, 0);
      asm("" : "+v"(d0), "+v"(d1));
      const int s16t = 16*t + 16;
      const int vt0 = tgq0 | s16t, vt1 = tgq1 | s16t,
                vt2 = tgq2 | s16t, vt3 = tgq3 | s16t;
      SCREEN1(d0[0], vt0, 0) SCREEN1(d0[1], vt1, 0)
      SCREEN1(d0[2], vt2, 0) SCREEN1(d0[3], vt3, 0)
      SCREEN1(d1[0], vt0, 1) SCREEN1(d1[1], vt1, 1)
      SCREEN1(d1[2], vt2, 1) SCREEN1(d1[3], vt3, 1)
    }
    pb += 128; pq += 8;
  }
#undef SCREEN1

  // quad-butterfly top-2 merge (lanes xor 16, 32 share the same row nn)
#pragma unroll
  for (int g = 0; g < 2; ++g) {
    float v1 = t1[g], v2 = t2[g];
#pragma unroll
    for (int m = 16; m < 64; m <<= 1) {
      float o1 = __shfl_xor(v1, m);
      float o2 = __shfl_xor(v2, m);
      float mn = fminf(v1, o1);
      v1 = fmaxf(v1, o1);
      v2 = fmaxf(mn, fmaxf(v2, o2));
    }
    if (quad == 0) wdump[wv][g*16 + nn] = make_float2(v1, v2);
  }
  __syncthreads();

  // merge 4 waves per row, unpack tags -> (l, code), apply -0.5*znorm here
  if (tid < RPB) {
    float v1 = -3.0e38f, v2 = -3.0e38f;
#pragma unroll
    for (int w = 0; w < 4; ++w) {
      float2 p = wdump[w][tid];
      float mn = fminf(v1, p.x);
      v1 = fmaxf(v1, p.x);
      v2 = fmaxf(mn, fmaxf(v2, p.y));
    }
    float znh = 0.5f * znorm[n0 + tid];
    int b1 = __float_as_int(v1), b2 = __float_as_int(v2);
    int c1i = blockIdx.y*CHUNK + (b1 & 0xFFF);
    int c2i = blockIdx.y*CHUNK + (b2 & 0xFFF);
    float l1 = 200.f * (__int_as_float(b1 & 0xFFFFF000) - znh);
    float l2 = 200.f * (__int_as_float(b2 & 0xFFFFF000) - znh);
    part[(size_t)blockIdx.y*NROWS + n0 + tid] =
        make_float4(l1, __int_as_float(c1i), l2, __int_as_float(c2i));
  }
}

// ---------------------------------------------------------------------------
// combine (+fused zq) — R12-exact, NO gate/finalize tail. R15 showed the
// fused tail's 256 serialized agent-scope atomic loads cost ~50+ us; the
// dispatch-boundary finalize with plain loads is ~5 us (R1..R12 proven).
// ---------------------------------------------------------------------------
__global__ __launch_bounds__(64) void combine_kernel(const float* __restrict__ z,
                                                     const float* __restrict__ emb,
                                                     float* __restrict__ ws,
                                                     float* __restrict__ out) {
  const float4* part = (const float4*)(ws + WS_PART);
  int n = blockIdx.x*64 + threadIdx.x;

  float l[16]; int c[16];
#pragma unroll
  for (int ch = 0; ch < KSPLIT; ++ch) {
    float4 v = part[(size_t)ch*NROWS + n];
    l[ch*2+0] = v.x; c[ch*2+0] = __float_as_int(v.y);
    l[ch*2+1] = v.z; c[ch*2+1] = __float_as_int(v.w);
  }
  float mm = l[0];
#pragma unroll
  for (int i = 1; i < 16; ++i) mm = fmaxf(mm, l[i]);

  int bb = n >> 8, hw = n & 255;
  float zr[32];
  float zn = 0.f;
#pragma unroll
  for (int cc = 0; cc < CDIM; ++cc) {
    zr[cc] = z[(size_t)bb*8192 + cc*256 + hw];
    zn = fmaf(zr[cc], zr[cc], zn);
  }
  float bd = 3.0e38f; int bc = 0x7fffffff;
#pragma unroll
  for (int i = 0; i < 16; ++i) {
    if (l[i] > mm - MARGIN) {
      int code = c[i];
      const float4* er4 = (const float4*)(emb + (size_t)code*CDIM);
      float dot = 0.f;
#pragma unroll
      for (int q = 0; q < 8; ++q) {
        float4 e4 = er4[q];
        dot = fmaf(zr[q*4+0], e4.x, dot);
        dot = fmaf(zr[q*4+1], e4.y, dot);
        dot = fmaf(zr[q*4+2], e4.z, dot);
        dot = fmaf(zr[q*4+3], e4.w, dot);
      }
      float d = (zn + ws[WS_ENORM + code]) - 2.f*dot;   // exact fp32 distance
      if (d < bd || (d == bd && code < bc)) { bd = d; bc = code; }
    }
  }
  out[OUT_IDX + n] = (float)bc;

  // fused zq: straight-through output + MSE (coalesced per-c stores)
  const float* er = emb + (size_t)bc*CDIM;
  float msel = 0.f;
#pragma unroll
  for (int cc = 0; cc < CDIM; ++cc) {
    float zq = er[cc];
    float df = zq - zr[cc];
    msel = fmaf(df, df, msel);
    out[(size_t)bb*8192 + cc*256 + hw] = zr[cc] + (zq - zr[cc]);
  }
  for (int off = 1; off < 64; off <<= 1) msel += __shfl_xor(msel, off);
  if (threadIdx.x == 0) atomicAdd(&ws[WS_MSE], msel);

  // loss softmax from approx pairs (max term = exp(0)=1 -> NaN-proof)
  float s = 0.f;
#pragma unroll
  for (int i = 0; i < 16; ++i) s += __expf(l[i] - mm);
  float lse = mm + __logf(s);

  float plp = 0.f;
#pragma unroll
  for (int i = 0; i < 16; ++i) {
    float u = l[i] - lse;
    float p = __expf(u);
    plp = fmaf(p, u, plp);
    if (p > 1e-12f) atomicAdd(&ws[WS_AVGP + c[i]], p);
  }
  for (int off = 1; off < 64; off <<= 1) plp += __shfl_xor(plp, off);
  if (threadIdx.x == 0) atomicAdd(&ws[WS_PLP], plp);
}

// ---------------------------------------------------------------------------
// finalize (separate dispatch, plain loads — R12-exact): entropy + loss.
// ---------------------------------------------------------------------------
__global__ __launch_bounds__(256) void finalize_kernel(const float* __restrict__ ws,
                                                       float* __restrict__ out) {
  __shared__ float red[256];
  float h = 0.f;
  for (int k = threadIdx.x; k < KCODES; k += 256) {
    float ap = ws[WS_AVGP + k] * (1.f/8192.f);
    h += ap * __logf(ap + 1e-5f);
  }
  red[threadIdx.x] = h;
  __syncthreads();
  for (int st = 128; st > 0; st >>= 1) {
    if (threadIdx.x < st) red[threadIdx.x] += red[threadIdx.x + st];
    __syncthreads();
  }
  if (threadIdx.x == 0) {
    float mse        = ws[WS_MSE] * (1.f/(8192.f*32.f));
    float sample_ent = -ws[WS_PLP] * (1.f/8192.f);
    out[OUT_LOSS] = 1.25f*mse + 0.1f*(sample_ent + red[0]);
  }
}

extern "C" void kernel_launch(void* const* d_in, const int* in_sizes, int n_in,
                              void* d_out, int out_size, void* d_ws, size_t ws_size,
                              hipStream_t stream) {
  (void)in_sizes; (void)n_in; (void)out_size; (void)ws_size;
  const float* z   = (const float*)d_in[0];
  const float* emb = (const float*)d_in[1];
  float* out = (float*)d_out;
  float* ws  = (float*)d_ws;

  prep_kernel    <<<96, 256, 0, stream>>>(z, emb, ws);
  gemm_pass      <<<dim3(NROWS/RPB, KSPLIT), 256, 0, stream>>>(ws, ws);
  combine_kernel <<<NROWS/64, 64, 0, stream>>>(z, emb, ws, out);
  finalize_kernel<<<1, 256, 0, stream>>>(ws, out);
}